// Round 7
// baseline (71.663 us; speedup 1.0000x reference)
//
#include <hip/hip_runtime.h>

typedef float f32x4 __attribute__((ext_vector_type(4)));

#define N_SAMPLES 64
#define M_ELEMS   307200            // 480*640 per-sample elements
#define M4        76800             // float4 per sample
#define BLOCK     256
#define BPS       30                // blocks per sample -> grid 1920 = 7.5 blk/CU
#define TPS       (BPS * BLOCK)     // 7680 threads per sample
#define GRP       5                 // pairs per pipeline group (10 iters total)
#define SCALE     (1.0f / ((float)M_ELEMS * (float)N_SAMPLES))

// Pin 5 a + 5 b float4 registers: loads can't sink below, consumes can't hoist above.
#define PIN_AB(a, b)                                                            \
    asm volatile("" : "+v"(a[0]), "+v"(a[1]), "+v"(a[2]), "+v"(a[3]), "+v"(a[4]),\
                      "+v"(b[0]), "+v"(b[1]), "+v"(b[2]), "+v"(b[3]), "+v"(b[4]) \
                    :: "memory");                                                \
    __builtin_amdgcn_sched_barrier(0)

__device__ __forceinline__ float wave_reduce_max(float v) {
    #pragma unroll
    for (int off = 32; off > 0; off >>= 1)
        v = fmaxf(v, __shfl_down(v, off, 64));
    return v;
}
__device__ __forceinline__ float wave_reduce_sum(float v) {
    #pragma unroll
    for (int off = 32; off > 0; off >>= 1)
        v += __shfl_down(v, off, 64);
    return v;
}

// Pass 1: per-sample max of |pred-targ|.
// VGPR budget <=64 (launch_bounds min 8 waves/EU) -> 8 waves/SIMD, ~94% occ.
// Rolling 5-pair pipeline keeps ~8-10 float4 loads outstanding per thread:
// in-flight bytes/CU ~ 1920 threads * 160B ~ 300KB — 4-7x every prior round.
__global__ __launch_bounds__(BLOCK, 8) void berhu_max_kernel(
        const float* __restrict__ pred,
        const float* __restrict__ targ,
        unsigned int* __restrict__ maxbits) {
    const int n = blockIdx.y;
    const f32x4* p = (const f32x4*)(pred + (size_t)n * M_ELEMS);
    const f32x4* t = (const f32x4*)(targ + (size_t)n * M_ELEMS);
    const int i0 = blockIdx.x * BLOCK + threadIdx.x;

    f32x4 a[GRP], b[GRP];
    #pragma unroll
    for (int k = 0; k < GRP; ++k) a[k] = p[i0 + k * TPS];
    #pragma unroll
    for (int k = 0; k < GRP; ++k) b[k] = t[i0 + k * TPS];
    PIN_AB(a, b);

    float m = 0.0f;
    // consume group 0 pair-by-pair, refilling the just-freed regs with group 1
    #pragma unroll
    for (int k = 0; k < GRP; ++k) {
        float m0 = fmaxf(fabsf(a[k][0] - b[k][0]), fabsf(a[k][1] - b[k][1]));
        float m1 = fmaxf(fabsf(a[k][2] - b[k][2]), fabsf(a[k][3] - b[k][3]));
        m = fmaxf(m, fmaxf(m0, m1));
        a[k] = p[i0 + (k + GRP) * TPS];
        b[k] = t[i0 + (k + GRP) * TPS];
    }
    PIN_AB(a, b);
    #pragma unroll
    for (int k = 0; k < GRP; ++k) {
        float m0 = fmaxf(fabsf(a[k][0] - b[k][0]), fabsf(a[k][1] - b[k][1]));
        float m1 = fmaxf(fabsf(a[k][2] - b[k][2]), fabsf(a[k][3] - b[k][3]));
        m = fmaxf(m, fmaxf(m0, m1));
    }

    m = wave_reduce_max(m);
    __shared__ float smax[BLOCK / 64];
    const int wid  = threadIdx.x >> 6;
    const int lane = threadIdx.x & 63;
    if (lane == 0) smax[wid] = m;
    __syncthreads();
    if (threadIdx.x == 0) {
        float bm = smax[0];
        #pragma unroll
        for (int w = 1; w < BLOCK / 64; ++w) bm = fmaxf(bm, smax[w]);
        atomicMax(&maxbits[n], __float_as_uint(bm));   // |d|>=0: bit cmp == float cmp
    }
}

// Pass 2: BerHu sum with the same rolling-pipeline read, scaled atomic into out[0].
__global__ __launch_bounds__(BLOCK, 8) void berhu_sum_kernel(
        const float* __restrict__ pred,
        const float* __restrict__ targ,
        const unsigned int* __restrict__ maxbits,
        float* __restrict__ out) {
    const int n = blockIdx.y;
    const float c = __uint_as_float(maxbits[n]) * 0.2f;   // max/5
    const float c2 = c * c;
    const float inv2c = (c > 0.0f) ? (0.5f / c) : 0.0f;

    const f32x4* p = (const f32x4*)(pred + (size_t)n * M_ELEMS);
    const f32x4* t = (const f32x4*)(targ + (size_t)n * M_ELEMS);
    const int i0 = blockIdx.x * BLOCK + threadIdx.x;

    f32x4 a[GRP], b[GRP];
    #pragma unroll
    for (int k = 0; k < GRP; ++k) a[k] = p[i0 + k * TPS];
    #pragma unroll
    for (int k = 0; k < GRP; ++k) b[k] = t[i0 + k * TPS];
    PIN_AB(a, b);

    float s = 0.0f;
    #pragma unroll
    for (int k = 0; k < GRP; ++k) {
        #pragma unroll
        for (int q = 0; q < 4; ++q) {
            float d = a[k][q] - b[k][q], ad = fabsf(d);
            s += (ad <= c) ? ad : (d * d + c2) * inv2c;
        }
        a[k] = p[i0 + (k + GRP) * TPS];
        b[k] = t[i0 + (k + GRP) * TPS];
    }
    PIN_AB(a, b);
    #pragma unroll
    for (int k = 0; k < GRP; ++k) {
        #pragma unroll
        for (int q = 0; q < 4; ++q) {
            float d = a[k][q] - b[k][q], ad = fabsf(d);
            s += (ad <= c) ? ad : (d * d + c2) * inv2c;
        }
    }

    s = wave_reduce_sum(s);
    __shared__ float ssum[BLOCK / 64];
    const int wid  = threadIdx.x >> 6;
    const int lane = threadIdx.x & 63;
    if (lane == 0) ssum[wid] = s;
    __syncthreads();
    if (threadIdx.x == 0) {
        float bs = ssum[0];
        #pragma unroll
        for (int w = 1; w < BLOCK / 64; ++w) bs += ssum[w];
        atomicAdd(out, bs * SCALE);
    }
}

extern "C" void kernel_launch(void* const* d_in, const int* in_sizes, int n_in,
                              void* d_out, int out_size, void* d_ws, size_t ws_size,
                              hipStream_t stream) {
    const float* pred = (const float*)d_in[0];
    const float* targ = (const float*)d_in[1];
    float* out = (float*)d_out;

    unsigned int* maxbits = (unsigned int*)d_ws;

    // ws/out poisoned 0xAA, not re-poisoned between replays — zero every call.
    hipMemsetAsync(d_ws, 0, N_SAMPLES * sizeof(unsigned int), stream);
    hipMemsetAsync(d_out, 0, sizeof(float), stream);

    dim3 grid(BPS, N_SAMPLES);
    berhu_max_kernel<<<grid, BLOCK, 0, stream>>>(pred, targ, maxbits);
    berhu_sum_kernel<<<grid, BLOCK, 0, stream>>>(pred, targ, maxbits, out);
}

// Round 8
// 68.613 us; speedup vs baseline: 1.0445x; 1.0445x over previous
//
#include <hip/hip_runtime.h>

typedef float f32x4 __attribute__((ext_vector_type(4)));

#define N_SAMPLES 64
#define M_ELEMS   307200            // 480*640 per-sample elements
#define M4        76800             // float4 per sample
#define BLOCK     256
#define BPS       25                // blocks per sample -> grid 1600 ~ 6.25/CU
#define TPS       (BPS * BLOCK)     // 6400 threads per sample
#define ITERS     12                // M4 / TPS exactly
#define STRIDE_B  102400            // TPS * 16 bytes = 0x19000
#define SCALE     (1.0f / ((float)M_ELEMS * (float)N_SAMPLES))

// One pred+targ pair of 16B loads sharing a voffset, then advance voffset.
// 0x19000 = 102400 = TPS*16. v_add_u32 takes the literal in src0 (VOP2 rule).
#define GLOAD2(Ai, Bi)                                            \
    "global_load_dwordx4 %[" #Ai "], %[off], %[PB]\n\t"           \
    "global_load_dwordx4 %[" #Bi "], %[off], %[TB]\n\t"           \
    "v_add_u32 %[off], 0x19000, %[off]\n\t"

__device__ __forceinline__ float wave_reduce_max(float v) {
    #pragma unroll
    for (int off = 32; off > 0; off >>= 1)
        v = fmaxf(v, __shfl_down(v, off, 64));
    return v;
}
__device__ __forceinline__ float wave_reduce_sum(float v) {
    #pragma unroll
    for (int off = 32; off > 0; off >>= 1)
        v += __shfl_down(v, off, 64);
    return v;
}

__device__ __forceinline__ float pairmax(f32x4 a, f32x4 b) {
    float m0 = fmaxf(fabsf(a[0] - b[0]), fabsf(a[1] - b[1]));
    float m1 = fmaxf(fabsf(a[2] - b[2]), fabsf(a[3] - b[3]));
    return fmaxf(m0, m1);
}

// Pass 1: per-sample max of |pred-targ| with an asm-guaranteed 12-deep
// (192 B/thread) load pipeline: the compiler cannot reorder, split, or
// serialize these loads. Two groups of 6 pairs, full drain between groups.
__global__ __launch_bounds__(BLOCK, 8) void berhu_max_kernel(
        const float* __restrict__ pred,
        const float* __restrict__ targ,
        unsigned int* __restrict__ maxbits) {
    const int n = blockIdx.y;
    const float* p = pred + (size_t)n * M_ELEMS;
    const float* t = targ + (size_t)n * M_ELEMS;
    unsigned int voff = (unsigned int)((blockIdx.x * BLOCK + threadIdx.x) * 16);

    f32x4 a0, a1, a2, a3, a4, a5, b0, b1, b2, b3, b4, b5;
    float m = 0.0f;

    // ---- group 0: issue 12 loads, single drain, consume ----
    asm volatile(
        GLOAD2(A0, B0) GLOAD2(A1, B1) GLOAD2(A2, B2)
        GLOAD2(A3, B3) GLOAD2(A4, B4) GLOAD2(A5, B5)
        "s_waitcnt vmcnt(0)\n\t"
        : [A0]"=&v"(a0), [A1]"=&v"(a1), [A2]"=&v"(a2),
          [A3]"=&v"(a3), [A4]"=&v"(a4), [A5]"=&v"(a5),
          [B0]"=&v"(b0), [B1]"=&v"(b1), [B2]"=&v"(b2),
          [B3]"=&v"(b3), [B4]"=&v"(b4), [B5]"=&v"(b5),
          [off]"+v"(voff)
        : [PB]"s"(p), [TB]"s"(t)
        : "memory");
    m = fmaxf(m, pairmax(a0, b0)); m = fmaxf(m, pairmax(a1, b1));
    m = fmaxf(m, pairmax(a2, b2)); m = fmaxf(m, pairmax(a3, b3));
    m = fmaxf(m, pairmax(a4, b4)); m = fmaxf(m, pairmax(a5, b5));

    // ---- group 1 ----
    asm volatile(
        GLOAD2(A0, B0) GLOAD2(A1, B1) GLOAD2(A2, B2)
        GLOAD2(A3, B3) GLOAD2(A4, B4) GLOAD2(A5, B5)
        "s_waitcnt vmcnt(0)\n\t"
        : [A0]"=&v"(a0), [A1]"=&v"(a1), [A2]"=&v"(a2),
          [A3]"=&v"(a3), [A4]"=&v"(a4), [A5]"=&v"(a5),
          [B0]"=&v"(b0), [B1]"=&v"(b1), [B2]"=&v"(b2),
          [B3]"=&v"(b3), [B4]"=&v"(b4), [B5]"=&v"(b5),
          [off]"+v"(voff)
        : [PB]"s"(p), [TB]"s"(t)
        : "memory");
    m = fmaxf(m, pairmax(a0, b0)); m = fmaxf(m, pairmax(a1, b1));
    m = fmaxf(m, pairmax(a2, b2)); m = fmaxf(m, pairmax(a3, b3));
    m = fmaxf(m, pairmax(a4, b4)); m = fmaxf(m, pairmax(a5, b5));

    m = wave_reduce_max(m);
    __shared__ float smax[BLOCK / 64];
    const int wid  = threadIdx.x >> 6;
    const int lane = threadIdx.x & 63;
    if (lane == 0) smax[wid] = m;
    __syncthreads();
    if (threadIdx.x == 0) {
        float bm = smax[0];
        #pragma unroll
        for (int w = 1; w < BLOCK / 64; ++w) bm = fmaxf(bm, smax[w]);
        atomicMax(&maxbits[n], __float_as_uint(bm));   // |d|>=0: bit cmp == float cmp
    }
}

// Pass 2: BerHu sum; inputs are L3-hot from pass 1 (~12 us measured in R1),
// plain loop suffices. Scaled atomic straight into out[0].
__global__ __launch_bounds__(BLOCK) void berhu_sum_kernel(
        const float* __restrict__ pred,
        const float* __restrict__ targ,
        const unsigned int* __restrict__ maxbits,
        float* __restrict__ out) {
    const int n = blockIdx.y;
    const float c = __uint_as_float(maxbits[n]) * 0.2f;   // max/5
    const float c2 = c * c;
    const float inv2c = (c > 0.0f) ? (0.5f / c) : 0.0f;

    const f32x4* p = (const f32x4*)(pred + (size_t)n * M_ELEMS);
    const f32x4* t = (const f32x4*)(targ + (size_t)n * M_ELEMS);

    float s = 0.0f;
    int i = blockIdx.x * BLOCK + threadIdx.x;
    #pragma unroll
    for (int k = 0; k < ITERS; ++k, i += TPS) {
        f32x4 a = p[i];
        f32x4 b = t[i];
        #pragma unroll
        for (int q = 0; q < 4; ++q) {
            float d = a[q] - b[q], ad = fabsf(d);
            s += (ad <= c) ? ad : (d * d + c2) * inv2c;
        }
    }

    s = wave_reduce_sum(s);
    __shared__ float ssum[BLOCK / 64];
    const int wid  = threadIdx.x >> 6;
    const int lane = threadIdx.x & 63;
    if (lane == 0) ssum[wid] = s;
    __syncthreads();
    if (threadIdx.x == 0) {
        float bs = ssum[0];
        #pragma unroll
        for (int w = 1; w < BLOCK / 64; ++w) bs += ssum[w];
        atomicAdd(out, bs * SCALE);
    }
}

extern "C" void kernel_launch(void* const* d_in, const int* in_sizes, int n_in,
                              void* d_out, int out_size, void* d_ws, size_t ws_size,
                              hipStream_t stream) {
    const float* pred = (const float*)d_in[0];
    const float* targ = (const float*)d_in[1];
    float* out = (float*)d_out;

    unsigned int* maxbits = (unsigned int*)d_ws;

    // ws/out poisoned 0xAA, not re-poisoned between replays — zero every call.
    hipMemsetAsync(d_ws, 0, N_SAMPLES * sizeof(unsigned int), stream);
    hipMemsetAsync(d_out, 0, sizeof(float), stream);

    dim3 grid(BPS, N_SAMPLES);
    berhu_max_kernel<<<grid, BLOCK, 0, stream>>>(pred, targ, maxbits);
    berhu_sum_kernel<<<grid, BLOCK, 0, stream>>>(pred, targ, maxbits, out);
}